// Round 10
// baseline (309.328 us; speedup 1.0000x reference)
//
#include <hip/hip_runtime.h>

// Round 10 = round 9 resubmitted verbatim (round-9 bench died at container
// acquire, same infra signature as round 3; the select/gather decomposition
// measurement never ran).

#define N_EMB  65536
#define DIM    512
#define K_C    256
#define NCHUNK 16     // 16 chunks x 32 dims
#define RPW    16     // rows per wave (select)
#define WAVES  4
#define THETA  1.5f   // rescore gate: ~14x approx-score error sigma

// ws layout: cbh = frag-ordered bf16-hi centroids (256 KiB) | cnorm = float[256] (1 KiB)
// Row indices pass select->gather embedded in out[row*DIM] (overwritten by gather).

typedef __attribute__((ext_vector_type(4))) float        f32x4;
typedef __attribute__((ext_vector_type(8))) __bf16       bf16x8;
typedef __attribute__((ext_vector_type(8))) short        s16x8;
typedef __attribute__((ext_vector_type(4))) unsigned int u32x4;

// ---- MFMA wrapper (rounds 1-8 verified). Primary: v8bf16; fallback v8i16.
template <class T>
__device__ inline auto mfma_bf16_t(T a, T b, f32x4 c, int)
    -> decltype(__builtin_amdgcn_mfma_f32_16x16x32_bf16(a, b, c, 0, 0, 0)) {
  return __builtin_amdgcn_mfma_f32_16x16x32_bf16(a, b, c, 0, 0, 0);
}
template <class T>
__device__ inline f32x4 mfma_bf16_t(T a, T b, f32x4 c, long) {
  return __builtin_amdgcn_mfma_f32_16x16x32_bf16(
      __builtin_bit_cast(s16x8, a), __builtin_bit_cast(s16x8, b), c, 0, 0, 0);
}
__device__ inline f32x4 MFMA(bf16x8 a, bf16x8 b, f32x4 c) {
  return mfma_bf16_t(a, b, c, 0);
}

__device__ inline unsigned umin_(unsigned a, unsigned b) { return a < b ? a : b; }
__device__ inline unsigned umax_(unsigned a, unsigned b) { return a > b ? a : b; }

// 8 fp32 -> packed bf16-hi via truncation (folds to v_perm pairs).
__device__ inline u32x4 pack8hi(const float4 a, const float4 b) {
  return (u32x4){
      (__float_as_uint(a.x) >> 16) | (__float_as_uint(a.y) & 0xFFFF0000u),
      (__float_as_uint(a.z) >> 16) | (__float_as_uint(a.w) & 0xFFFF0000u),
      (__float_as_uint(b.x) >> 16) | (__float_as_uint(b.y) & 0xFFFF0000u),
      (__float_as_uint(b.z) >> 16) | (__float_as_uint(b.w) & 0xFFFF0000u)};
}

__device__ inline u32x4 cvt8hi_rne(const float4 a, const float4 b) {
  float v[8] = {a.x, a.y, a.z, a.w, b.x, b.y, b.z, b.w};
  unsigned h[8];
#pragma unroll
  for (int i = 0; i < 8; ++i) {  // RNE for centroids (prep is cheap, keep quality)
    const unsigned u = __float_as_uint(v[i]);
    h[i] = (u + 0x7FFFu + ((u >> 16) & 1u)) >> 16;
  }
  return (u32x4){h[0] | (h[1] << 16), h[2] | (h[3] << 16),
                 h[4] | (h[5] << 16), h[6] | (h[7] << 16)};
}

// ---- prep (fused): frag-ordered bf16-hi centroids + exact fp32 norms.
// Frag element: lane L of [chunk][ct] block holds C[ct*16+(L&15)][chunk*32+(L>>4)*8+j].
__global__ void pack_centroids(const float* __restrict__ cent,
                               unsigned* __restrict__ cbh,
                               float* __restrict__ cnorm) {
  const int k    = blockIdx.x;   // centroid
  const int lane = threadIdx.x;  // 0..63, dims lane*8..+7
  const float* src = cent + (size_t)k * DIM + lane * 8;
  const float4 a = *(const float4*)src;
  const float4 b = *(const float4*)(src + 4);
  const int chunk = lane >> 2, g = lane & 3;
  ((u32x4*)cbh)[((size_t)chunk * 16 + (k >> 4)) * 64 + g * 16 + (k & 15)] =
      cvt8hi_rne(a, b);
  float s = a.x * a.x + a.y * a.y + a.z * a.z + a.w * a.w +
            b.x * b.x + b.y * b.y + b.z * b.z + b.w * b.w;
#pragma unroll
  for (int off = 32; off > 0; off >>= 1) s += __shfl_down(s, off, 64);
  if (lane == 0) cnorm[k] = s;
}

// ---- select: R6's verified wave-autonomous body, minus gather/write.
// 16 rows/wave, all 256 centroids, C register-double-buffered from L2, E frags
// direct from global (R8 proved access pattern is not the bottleneck).
// Emits ONLY the winning index, bit-stashed in out[row*DIM] (gather overwrites).
__global__ __launch_bounds__(256, 4)
void select_kernel(const float* __restrict__ emb,
                   const float* __restrict__ cent,
                   const unsigned* __restrict__ cbh,
                   const float* __restrict__ cnorm,
                   float* __restrict__ out) {
  __shared__ unsigned top4s[WAVES][RPW][4];  // per-wave private, no barriers

  const int tid  = threadIdx.x;
  const int lane = tid & 63;
  const int w    = tid >> 6;
  const int row0 = (blockIdx.x * WAVES + w) * RPW;  // this wave's 16 rows
  const int frow = lane & 15, fgrp = lane >> 4;

  f32x4 acc[16];
#pragma unroll
  for (int j = 0; j < 16; ++j) acc[j] = (f32x4){0.f, 0.f, 0.f, 0.f};

  // A-frag source: lane L covers E[row0 + (L&15)][c*32 + (L>>4)*8 .. +7]
  const float* const ep = emb + (size_t)(row0 + frow) * DIM + fgrp * 8;
  float4 ea = *(const float4*)(ep);
  float4 eb = *(const float4*)(ep + 4);

  // Rolling C double-buffer: A = current half-chunk (8 frags), B = next.
  const u32x4* const cs = (const u32x4*)cbh + lane;
  u32x4 A[8], B[8];
#pragma unroll
  for (int i = 0; i < 8; ++i) A[i] = cs[i * 64];
#pragma unroll
  for (int i = 0; i < 8; ++i) B[i] = cs[512 + i * 64];

  for (int c = 0; c < NCHUNK; ++c) {
    const int cn = (c + 1) & (NCHUNK - 1);
    const float4 na = *(const float4*)(ep + cn * 32);      // E chunk c+1
    const float4 nb = *(const float4*)(ep + cn * 32 + 4);
    const bf16x8 eh = __builtin_bit_cast(bf16x8, pack8hi(ea, eb));

#pragma unroll
    for (int i = 0; i < 8; ++i)
      acc[i] = MFMA(eh, __builtin_bit_cast(bf16x8, A[i]), acc[i]);
    const u32x4* const csn = cs + (size_t)cn * 1024;       // refill A <- (c+1,h0)
#pragma unroll
    for (int i = 0; i < 8; ++i) A[i] = csn[i * 64];

#pragma unroll
    for (int i = 0; i < 8; ++i)
      acc[8 + i] = MFMA(eh, __builtin_bit_cast(bf16x8, B[i]), acc[8 + i]);
#pragma unroll
    for (int i = 0; i < 8; ++i) B[i] = csn[512 + i * 64];  // refill B <- (c+1,h1)

    ea = na; eb = nb;
  }

  // ---- approx top-4 per row. D map: E-row=(lane>>4)*4+reg, cent-col=lane&15.
  const int lcol = lane & 15, lgrp = lane >> 4;
  float cnv[16];
#pragma unroll
  for (int ct = 0; ct < 16; ++ct) cnv[ct] = cnorm[ct * 16 + lcol];

#pragma unroll
  for (int rg = 0; rg < 4; ++rg) {
    unsigned b0_ = 0xFFFFFFFFu, b1_ = b0_, b2_ = b0_, b3_ = b0_;
    auto ins = [&](unsigned u) {
      b3_ = umin_(b3_, umax_(b2_, u));
      b2_ = umin_(b2_, umax_(b1_, u));
      b1_ = umin_(b1_, umax_(b0_, u));
      b0_ = umin_(b0_, u);
    };
#pragma unroll
    for (int ct = 0; ct < 16; ++ct) {
      const float s = fmaf(-2.f, acc[ct][rg], cnv[ct]);  // ||e||^2 drops
      ins((__float_as_uint(s) & 0xFFFFFF00u) | (unsigned)(ct * 16 + lcol));
    }
#pragma unroll
    for (int off = 1; off < 16; off <<= 1) {  // merge 16 col-lanes of the group
      const unsigned o0 = __shfl_xor(b0_, off, 64);
      const unsigned o1 = __shfl_xor(b1_, off, 64);
      const unsigned o2 = __shfl_xor(b2_, off, 64);
      const unsigned o3 = __shfl_xor(b3_, off, 64);
      ins(o0); ins(o1); ins(o2); ins(o3);
    }
    if (lcol == 0) {
      const int rl = lgrp * 4 + rg;  // row within wave
      *(u32x4*)&top4s[w][rl][0] = (u32x4){b0_, b1_, b2_, b3_};
    }
  }
  // same-wave ds_write -> ds_read: compiler inserts lgkmcnt, no barrier needed

  // ---- theta-gate + exact fp32 rescore where needed; emit index only.
  for (int rr = 0; rr < RPW; ++rr) {
    const int grow = row0 + rr;
    const unsigned u0 = top4s[w][rr][0], u1 = top4s[w][rr][1];
    const unsigned u2 = top4s[w][rr][2], u3 = top4s[w][rr][3];
    const float a0s = __uint_as_float(u0 & 0xFFFFFF00u);
    const float a1s = __uint_as_float(u1 & 0xFFFFFF00u);
    const float a2s = __uint_as_float(u2 & 0xFFFFFF00u);
    int i2;
    if (a1s - a0s >= THETA && a2s - a1s >= THETA) {
      i2 = (int)(u1 & 0xFFu);  // provably the true 2nd-nearest
    } else {
      const int c0 = (int)(u0 & 0xFFu), c1 = (int)(u1 & 0xFFu);
      const int c2 = (int)(u2 & 0xFFu), c3 = (int)(u3 & 0xFFu);

      const float4* e4 = (const float4*)(emb + (size_t)grow * DIM) + lane * 2;
      const float4 ev0 = e4[0], ev1 = e4[1];
      auto pdot = [&](int cj) {
        const float4* c4 = (const float4*)(cent + (size_t)cj * DIM) + lane * 2;
        const float4 cv0 = c4[0], cv1 = c4[1];
        float d = ev0.x * cv0.x;
        d = fmaf(ev0.y, cv0.y, d); d = fmaf(ev0.z, cv0.z, d);
        d = fmaf(ev0.w, cv0.w, d);
        d = fmaf(ev1.x, cv1.x, d); d = fmaf(ev1.y, cv1.y, d);
        d = fmaf(ev1.z, cv1.z, d); d = fmaf(ev1.w, cv1.w, d);
        return d;
      };
      float d0 = pdot(c0), d1 = pdot(c1), d2 = pdot(c2), d3 = pdot(c3);
#pragma unroll
      for (int off = 1; off < 64; off <<= 1) {  // 4 independent chains
        d0 += __shfl_xor(d0, off, 64);
        d1 += __shfl_xor(d1, off, 64);
        d2 += __shfl_xor(d2, off, 64);
        d3 += __shfl_xor(d3, off, 64);
      }
      const float s0 = fmaf(-2.f, d0, cnorm[c0]);
      const float s1 = fmaf(-2.f, d1, cnorm[c1]);
      const float s2 = fmaf(-2.f, d2, cnorm[c2]);
      const float s3 = fmaf(-2.f, d3, cnorm[c3]);

      float v1 = s0, v2 = 3.4e38f;
      int i1 = c0; i2 = K_C;
      auto upd = [&](float s, int ci) {  // stable smaller-index tiebreak
        if (s < v1 || (s == v1 && ci < i1)) { v2 = v1; i2 = i1; v1 = s; i1 = ci; }
        else if (s < v2 || (s == v2 && ci < i2)) { v2 = s; i2 = ci; }
      };
      upd(s1, c1); upd(s2, c2); upd(s3, c3);
    }
    if (lane == 0)
      out[(size_t)grow * DIM] = __uint_as_float((unsigned)i2);  // idx stash
  }
}

// ---- gather: pure streaming copy at max occupancy. 8 rows/block; idx read
// from the stash (barrier separates all reads from the overwrite), then fully
// coalesced 16B stores from the L2-hot centroid table.
__global__ __launch_bounds__(256, 8)
void gather_kernel(const float* __restrict__ cent, float* __restrict__ out) {
  __shared__ unsigned sidx[8];
  const int tid = threadIdx.x;
  const int r0  = blockIdx.x * 8;
  if (tid < 8)
    sidx[tid] = __float_as_uint(out[(size_t)(r0 + tid) * DIM]) & 255u;
  __syncthreads();
  const float4* c4 = (const float4*)cent;
  float4* o4 = (float4*)(out + (size_t)r0 * DIM);
#pragma unroll
  for (int j = 0; j < 4; ++j) {
    const int g = j * 256 + tid;       // 1024 float4 = 8 rows of 128
    const int rrel = g >> 7, off = g & 127;
    o4[g] = c4[sidx[rrel] * 128 + off];
  }
}

extern "C" void kernel_launch(void* const* d_in, const int* in_sizes, int n_in,
                              void* d_out, int out_size, void* d_ws, size_t ws_size,
                              hipStream_t stream) {
  (void)in_sizes; (void)n_in; (void)out_size; (void)ws_size;
  const float* emb  = (const float*)d_in[0];
  const float* cent = (const float*)d_in[1];
  // d_in[2] = batch_id, unused.
  unsigned* cbh = (unsigned*)d_ws;                     // 256 KiB frag-ordered C-hi
  float* cnorm  = (float*)((char*)d_ws + 256 * 1024);  // 1 KiB

  pack_centroids<<<K_C, 64, 0, stream>>>(cent, cbh, cnorm);
  select_kernel<<<N_EMB / (WAVES * RPW), 256, 0, stream>>>(emb, cent, cbh, cnorm,
                                                           (float*)d_out);
  gather_kernel<<<N_EMB / 8, 256, 0, stream>>>(cent, (float*)d_out);
}